// Round 7
// baseline (257.608 us; speedup 1.0000x reference)
//
#include <hip/hip_runtime.h>
#include <string.h>

#define NN 30000
#define NE 480000
#define CAP 96
#define KSC (0.0625f * 1.44269504f)   // SCALE * log2(e): exp(q*k/16) = exp2(q*kk)

typedef __attribute__((ext_vector_type(8))) _Float16 f16x8;
typedef __attribute__((ext_vector_type(4))) float f32x4;
typedef __attribute__((ext_vector_type(4))) int i32x4;

__device__ __forceinline__ unsigned short f2h(float f) {
    _Float16 h = (_Float16)f;
    unsigned short u;
    memcpy(&u, &h, 2);
    return u;
}

__device__ __forceinline__ void gload16(const void* g, void* l) {
    __builtin_amdgcn_global_load_lds(
        (const __attribute__((address_space(1))) unsigned int*)g,
        (__attribute__((address_space(3))) unsigned int*)l, 16, 0, 0);
}

// ---------------- LayerNorm -> fp16 x ----------------
__global__ __launch_bounds__(256) void ln_kernel(const float* __restrict__ s,
                                                 const float* __restrict__ gamma,
                                                 const float* __restrict__ beta,
                                                 unsigned short* __restrict__ xh) {
    const int n = blockIdx.x;
    const int c = threadIdx.x;
    float v = s[n * 256 + c];
    float sum = v, sq = v * v;
    for (int o = 32; o; o >>= 1) {
        sum += __shfl_down(sum, o, 64);
        sq  += __shfl_down(sq,  o, 64);
    }
    __shared__ float ssum[4], ssq[4];
    const int wave = c >> 6, lane = c & 63;
    if (lane == 0) { ssum[wave] = sum; ssq[wave] = sq; }
    __syncthreads();
    float ts = ssum[0] + ssum[1] + ssum[2] + ssum[3];
    float tq = ssq[0]  + ssq[1]  + ssq[2]  + ssq[3];
    float mu  = ts * (1.0f / 256.0f);
    float var = tq * (1.0f / 256.0f) - mu * mu;
    float x = (v - mu) * rsqrtf(var + 1e-5f) * gamma[c] + beta[c];
    xh[n * 256 + c] = f2h(x);
}

// ---------------- Wqkv [256,768] f32 -> WT [768,256] fp16 ----------------
__global__ __launch_bounds__(256) void wt_kernel(const float* __restrict__ W,
                                                 unsigned short* __restrict__ WT) {
    const int idx = blockIdx.x * 256 + threadIdx.x;
    if (idx < 768 * 256) {
        const int n = idx >> 8;
        const int k = idx & 255;
        WT[idx] = f2h(W[k * 768 + n]);
    }
}

__global__ __launch_bounds__(256) void zero_kernel(int* __restrict__ p, int n) {
    const int i = blockIdx.x * 256 + threadIdx.x;
    if (i < n) p[i] = 0;
}

__global__ __launch_bounds__(256) void scatter_kernel(const int* __restrict__ src,
                                                      const int* __restrict__ dst,
                                                      int* __restrict__ cursor,
                                                      unsigned short* __restrict__ col) {
    const int e = blockIdx.x * 256 + threadIdx.x;
    if (e < NE) {
        const int d = dst[e];
        const int slot = atomicAdd(&cursor[d], 1);
        if (slot < CAP) col[d * CAP + slot] = (unsigned short)src[e];
    }
}

// ---------------- GEMM: m97-style, XCD-banded, epilogue -> qvi/ks sliced ----------------
#define BM 128
#define BN 128
#define BK 32
#define CSTRIDE 136
#define MTILES 235   // ceil(30000/128)

__global__ __launch_bounds__(256) void gemm_kernel(const unsigned short* __restrict__ A,
                                                   const unsigned short* __restrict__ B,
                                                   unsigned short* __restrict__ qvi,  // [8][NN][4grp][8q,8v]
                                                   unsigned short* __restrict__ ks) { // [8][NN][32]
    const int f   = blockIdx.x;          // 0..1439
    const int xcd = f & 7;
    const int i   = f >> 3;              // 0..179
    const int bmi = xcd * 30 + i / 6;
    if (bmi >= MTILES) return;
    const int bm = bmi * BM;
    const int by = i % 6;
    const int bn = by * BN;

    __shared__ unsigned short smem[BM * CSTRIDE];
    unsigned short* As = smem;
    unsigned short* Bs = smem + 4096;

    const int tid  = threadIdx.x;
    const int lane = tid & 63;
    const int wave = tid >> 6;
    const int wm = (wave & 1) * 64;
    const int wn = (wave >> 1) * 64;
    const int l16  = lane & 15;
    const int quad = lane >> 4;

    const int srow = wave * 16 + (lane >> 2);
    const int ko   = (lane & 3) * 8;

    int gmA0 = bm + srow;       if (gmA0 >= NN) gmA0 = NN - 1;
    int gmA1 = bm + srow + 64;  if (gmA1 >= NN) gmA1 = NN - 1;
    const int gnB0 = bn + srow;
    const int gnB1 = bn + srow + 64;

    f32x4 acc[4][4] = {};

    for (int kt = 0; kt < 256; kt += BK) {
        gload16(A + (size_t)gmA0 * 256 + kt + ko, &As[(wave * 16) * 32]);
        gload16(A + (size_t)gmA1 * 256 + kt + ko, &As[(64 + wave * 16) * 32]);
        gload16(B + (size_t)gnB0 * 256 + kt + ko, &Bs[(wave * 16) * 32]);
        gload16(B + (size_t)gnB1 * 256 + kt + ko, &Bs[(64 + wave * 16) * 32]);
        __syncthreads();

        f16x8 af[4], bfr[4];
        #pragma unroll
        for (int ii = 0; ii < 4; ii++)
            af[ii]  = *(const f16x8*)(&As[(wm + ii * 16 + l16) * 32 + quad * 8]);
        #pragma unroll
        for (int j = 0; j < 4; j++)
            bfr[j] = *(const f16x8*)(&Bs[(wn + j * 16 + l16) * 32 + quad * 8]);
        #pragma unroll
        for (int ii = 0; ii < 4; ii++)
            #pragma unroll
            for (int j = 0; j < 4; j++)
                acc[ii][j] = __builtin_amdgcn_mfma_f32_16x16x32_f16(af[ii], bfr[j], acc[ii][j], 0, 0, 0);
        __syncthreads();
    }

    #pragma unroll
    for (int ii = 0; ii < 4; ii++)
        #pragma unroll
        for (int j = 0; j < 4; j++)
            #pragma unroll
            for (int r = 0; r < 4; r++)
                smem[(wm + ii * 16 + quad * 4 + r) * CSTRIDE + wn + j * 16 + l16] =
                    f2h(acc[ii][j][r]);
    __syncthreads();

    const int sector  = by >> 1;                 // 0=q,1=k,2=v
    const int colhalf = (by & 1) * 128;
    const int row  = tid >> 1;
    const int cseg = (tid & 1) * 64;
    const int grow = bm + row;
    if (grow < NN) {
        #pragma unroll
        for (int k = 0; k < 8; k++) {
            i32x4 val = *(const i32x4*)(&smem[row * CSTRIDE + cseg + k * 8]);
            const int c   = colhalf + cseg + k * 8;    // 8-aligned, 0..255
            const int x   = c >> 5;                    // slice
            const int grp = (c >> 3) & 3;              // 8-ch group
            if (sector == 1)
                *(i32x4*)(ks + ((size_t)x * NN + grow) * 32 + (c & 31)) = val;
            else
                *(i32x4*)(qvi + ((size_t)x * NN + grow) * 64 + grp * 16 +
                          (sector == 0 ? 0 : 8)) = val;
        }
    }
}

// ---------------- edge: slice-per-XCD, NODE-PER-WAVE, uniform scalar loop ----------------
__global__ __launch_bounds__(256) void edge_kernel(const unsigned short* __restrict__ qvi, // [8][NN][64]
                                                   const unsigned short* __restrict__ ks,  // [8][NN][32]
                                                   const int* __restrict__ cursor,
                                                   const unsigned short* __restrict__ col, // [NN][CAP]
                                                   float* __restrict__ out) {
    const int x   = blockIdx.x;            // slice 0..7 -> XCD (round-robin, validated r5/r6)
    const int nb  = blockIdx.y * 4;        // block's 4 nodes
    const int tid = threadIdx.x;

    __shared__ int scol[4 * CAP];          // byte offsets (src*128), 1536 B
    __shared__ int sdeg[4];

    if (tid < 192) {
        const unsigned int u = ((const unsigned int*)(col + (size_t)nb * CAP))[tid];
        scol[2 * tid]     = (int)(u & 0xffffu) << 7;
        scol[2 * tid + 1] = (int)(u >> 16) << 7;
    }
    if (tid < 4) {
        int d = cursor[nb + tid];
        sdeg[tid] = (d > CAP) ? CAP : d;
    }
    __syncthreads();

    const int w    = tid >> 6;             // wave = node
    const int lane = tid & 63;
    const int h    = lane >> 5;            // edge parity
    const int ch   = lane & 31;            // channel within slice
    const int n    = nb + w;

    const int deg = __builtin_amdgcn_readfirstlane(sdeg[w]);

    const float kk = (float)(*(const _Float16*)(ks + ((size_t)x * NN + n) * 32 + ch)) * KSC;

    const char* qbase = (const char*)qvi + (size_t)x * NN * 128;
    const int   loff  = ((ch >> 3) * 32) + ((ch & 7) * 2);   // q byte offset in node row
    const int   sb    = w * CAP + h;                          // scol base, stride 2

    float z = 0.0f, a = 0.0f;

    const int T = deg >> 1;
    int t = 0;
    for (; t + 4 <= T; t += 4) {
        const int o0 = scol[sb + 2 * t];
        const int o1 = scol[sb + 2 * t + 2];
        const int o2 = scol[sb + 2 * t + 4];
        const int o3 = scol[sb + 2 * t + 6];
        const char* p0 = qbase + o0 + loff;
        const char* p1 = qbase + o1 + loff;
        const char* p2 = qbase + o2 + loff;
        const char* p3 = qbase + o3 + loff;
        const float q0 = (float)*(const _Float16*)p0;
        const float v0 = (float)*(const _Float16*)(p0 + 16);
        const float q1 = (float)*(const _Float16*)p1;
        const float v1 = (float)*(const _Float16*)(p1 + 16);
        const float q2 = (float)*(const _Float16*)p2;
        const float v2 = (float)*(const _Float16*)(p2 + 16);
        const float q3 = (float)*(const _Float16*)p3;
        const float v3 = (float)*(const _Float16*)(p3 + 16);
        const float w0 = __builtin_exp2f(q0 * kk);
        const float w1 = __builtin_exp2f(q1 * kk);
        const float w2 = __builtin_exp2f(q2 * kk);
        const float w3 = __builtin_exp2f(q3 * kk);
        z += w0; a += w0 * v0;
        z += w1; a += w1 * v1;
        z += w2; a += w2 * v2;
        z += w3; a += w3 * v3;
    }
    for (; t < T; ++t) {
        const int o = scol[sb + 2 * t];
        const char* p = qbase + o + loff;
        const float q = (float)*(const _Float16*)p;
        const float v = (float)*(const _Float16*)(p + 16);
        const float wt = __builtin_exp2f(q * kk);
        z += wt; a += wt * v;
    }
    if ((deg & 1) && h == 0) {             // odd tail: edge deg-1, lower half only
        const int o = scol[w * CAP + deg - 1];
        const char* p = qbase + o + loff;
        const float q = (float)*(const _Float16*)p;
        const float v = (float)*(const _Float16*)(p + 16);
        const float wt = __builtin_exp2f(q * kk);
        z += wt; a += wt * v;
    }

    z += __shfl_xor(z, 32, 64);
    a += __shfl_xor(a, 32, 64);
    if (h == 0)
        out[(size_t)n * 256 + x * 32 + ch] = (deg > 0) ? a / z : 0.0f;
}

extern "C" void kernel_launch(void* const* d_in, const int* in_sizes, int n_in,
                              void* d_out, int out_size, void* d_ws, size_t ws_size,
                              hipStream_t stream) {
    const float* s     = (const float*)d_in[0];
    const float* Wqkv  = (const float*)d_in[1];
    const float* gamma = (const float*)d_in[2];
    const float* beta  = (const float*)d_in[3];
    const int*   src   = (const int*)d_in[4];
    const int*   dst   = (const int*)d_in[5];
    float* out = (float*)d_out;

    char* ws = (char*)d_ws;
    unsigned short* xh  = (unsigned short*)(ws);                    // 15,360,000 B
    unsigned short* WT  = (unsigned short*)(ws + 15360000);         //    393,216 B
    unsigned short* qvi = (unsigned short*)(ws + 15753216);         // 30,720,000 B [8][NN][64]
    unsigned short* ks  = (unsigned short*)(ws + 46473216);         // 15,360,000 B [8][NN][32]
    int*            cur = (int*)(ws + 61833216);                    //    120,000 B
    unsigned short* col = (unsigned short*)(ws + 61953216);         //  5,760,000 B (~67.7 MB)

    ln_kernel<<<NN, 256, 0, stream>>>(s, gamma, beta, xh);
    wt_kernel<<<(768 * 256 + 255) / 256, 256, 0, stream>>>(Wqkv, WT);
    zero_kernel<<<(NN + 255) / 256, 256, 0, stream>>>(cur, NN);
    scatter_kernel<<<(NE + 255) / 256, 256, 0, stream>>>(src, dst, cur, col);
    gemm_kernel<<<1440, 256, 0, stream>>>(xh, WT, qvi, ks);
    edge_kernel<<<dim3(8, NN / 4), 256, 0, stream>>>(qvi, ks, cur, col, out);
}